// Round 11
// baseline (386.369 us; speedup 1.0000x reference)
//
#include <hip/hip_runtime.h>
#include <hip/hip_cooperative_groups.h>
#include <math.h>

namespace cg = cooperative_groups;

#define DMODEL 512
#define NSEQ 2048
#define NHEAD 8
#define DK 64
#define DV 64
#define MFEAT 266
#define MPAD 288        // padded feature dim for bf16 MFMA (zero tail), mult of 32
#define NT 32           // number of chunks (chunk = 64)
#define LN_EPS 1e-6f
#define KERNEL_EPS 1e-4f
#define NORM_STAB 1e-6f
#define SCALE 0.21022410381342863f  // 512^-0.25

typedef __attribute__((ext_vector_type(8))) short short8;
typedef __attribute__((ext_vector_type(4))) short sv4;
typedef __attribute__((ext_vector_type(4))) float f32x4;

__device__ inline short f2bf(float f) {
    unsigned u = __builtin_bit_cast(unsigned, f);
    unsigned r = (u + 0x7fff + ((u >> 16) & 1)) >> 16;
    return (short)r;
}
__device__ inline float bf2f(short s) {
    unsigned u = ((unsigned)(unsigned short)s) << 16;
    return __builtin_bit_cast(float, u);
}

// ============ phase bodies (shared by mega-kernel and fallback kernels) ============

// ---- QKV GEMM tile; z=0 inline-LN, z=1 emits h_k + max partials. smem: 10256 B ----
__device__ __forceinline__ void qkv_body(char* smem, int bx, int by, int z,
                                         const float* __restrict__ qx,
                                         const float* __restrict__ kx,
                                         const float* __restrict__ vx,
                                         const float* __restrict__ Wq,
                                         const float* __restrict__ Wk,
                                         const float* __restrict__ Wv,
                                         const float* __restrict__ gamma,
                                         const float* __restrict__ beta,
                                         short* __restrict__ qh,
                                         short* __restrict__ kh,
                                         short* __restrict__ vh,
                                         float* __restrict__ hk,
                                         float* __restrict__ partial) {
    const float* A = (z == 0) ? qx : (z == 1) ? kx : vx;
    const float* B = (z == 0) ? Wq : (z == 1) ? Wk : Wv;
    short* C = (z == 0) ? qh : (z == 1) ? kh : vh;
    float scale = (z == 2) ? 1.f : SCALE;
    auto As = (short(*)[40])smem;
    auto Bs = (short(*)[40])(smem + 5120);
    float* bmax = (float*)(smem + 10240);
    int bm = by * 64, bn = bx * 64;
    int tid = threadIdx.x;
    int wid = tid >> 6, lane = tid & 63;
    f32x4 acc[4] = {f32x4{0,0,0,0}, f32x4{0,0,0,0}, f32x4{0,0,0,0}, f32x4{0,0,0,0}};
    int ar = tid >> 2, akq = tid & 3;
    int bkk = tid >> 3, bng = tid & 7;
    float lnm = 0.f, lnr = 0.f;
    if (z == 0) {
        const float* xr = qx + (size_t)(bm + ar) * DMODEL + akq * 128;
        float s = 0.f, ss = 0.f;
#pragma unroll 4
        for (int i = 0; i < 128; i += 4) {
            f32x4 vv = *(const f32x4*)(xr + i);
            s += vv[0] + vv[1] + vv[2] + vv[3];
            ss += vv[0]*vv[0] + vv[1]*vv[1] + vv[2]*vv[2] + vv[3]*vv[3];
        }
        s += __shfl_xor(s, 1); s += __shfl_xor(s, 2);
        ss += __shfl_xor(ss, 1); ss += __shfl_xor(ss, 2);
        float m = s / (float)DMODEL;
        float var = ss / (float)DMODEL - m * m;
        lnm = m;
        lnr = rsqrtf(var + LN_EPS);
    }
    for (int k0 = 0; k0 < DMODEL; k0 += 32) {
        {
            const float* src = A + (size_t)(bm + ar) * DMODEL + k0 + akq * 8;
            f32x4 v0 = *(const f32x4*)src;
            f32x4 v1 = *(const f32x4*)(src + 4);
            short8 sv;
            if (z == 0) {
                f32x4 g0 = *(const f32x4*)&gamma[k0 + akq * 8];
                f32x4 g1 = *(const f32x4*)&gamma[k0 + akq * 8 + 4];
                f32x4 bb0 = *(const f32x4*)&beta[k0 + akq * 8];
                f32x4 bb1 = *(const f32x4*)&beta[k0 + akq * 8 + 4];
                for (int j = 0; j < 4; ++j) {
                    sv[j] = f2bf((v0[j] - lnm) * lnr * g0[j] + bb0[j]);
                    sv[4 + j] = f2bf((v1[j] - lnm) * lnr * g1[j] + bb1[j]);
                }
            } else {
                for (int j = 0; j < 4; ++j) { sv[j] = f2bf(v0[j]); sv[4 + j] = f2bf(v1[j]); }
            }
            *(short8*)&As[ar][akq * 8] = sv;
        }
        {
            const float* src = B + (size_t)(k0 + bkk) * DMODEL + bn + bng * 8;
            f32x4 v0 = *(const f32x4*)src;
            f32x4 v1 = *(const f32x4*)(src + 4);
            for (int j = 0; j < 4; ++j) {
                Bs[bng * 8 + j][bkk] = f2bf(v0[j] * scale);
                Bs[bng * 8 + 4 + j][bkk] = f2bf(v1[j] * scale);
            }
        }
        __syncthreads();
        int row = wid * 16 + (lane & 15);
        int koff = (lane >> 4) * 8;
        short8 a = *(const short8*)&As[row][koff];
        for (int nf = 0; nf < 4; ++nf) {
            int col = nf * 16 + (lane & 15);
            short8 b = *(const short8*)&Bs[col][koff];
            acc[nf] = __builtin_amdgcn_mfma_f32_16x16x32_bf16(a, b, acc[nf], 0, 0, 0);
        }
        __syncthreads();
    }
    for (int nf = 0; nf < 4; ++nf) {
        int col = bn + nf * 16 + (lane & 15);
        for (int j = 0; j < 4; ++j) {
            int row = bm + wid * 16 + (lane >> 4) * 4 + j;
            C[(size_t)row * DMODEL + col] = f2bf(acc[nf][j]);
        }
    }
    if (z == 1) {
        float hvmax = -1e30f;
        for (int j = 0; j < 4; ++j) {
            float ss = 0.f;
            for (int nf = 0; nf < 4; ++nf) ss += acc[nf][j] * acc[nf][j];
            for (int o = 1; o < 16; o <<= 1) ss += __shfl_xor(ss, o);
            float hv = -0.5f * ss;
            int row = bm + wid * 16 + (lane >> 4) * 4 + j;
            if ((lane & 15) == 0) hk[(size_t)bx * NSEQ + row] = hv;
            hvmax = fmaxf(hvmax, hv);
        }
        for (int o = 32; o > 0; o >>= 1) hvmax = fmaxf(hvmax, __shfl_down(hvmax, o));
        if (lane == 0) bmax[wid] = hvmax;
        __syncthreads();
        if (tid == 0)
            partial[by * 8 + bx] = fmaxf(fmaxf(bmax[0], bmax[1]), fmaxf(bmax[2], bmax[3]));
    }
}

// ---- feature map tile (MFMA). smem: 50704 B ----
__device__ __forceinline__ void feat_body(char* smem, int nt, int h, int isQ,
                                          const short* __restrict__ qh,
                                          const short* __restrict__ kh,
                                          const float* __restrict__ rf,
                                          const float* __restrict__ hkv,
                                          const float* __restrict__ partial,
                                          short* __restrict__ qp,
                                          short* __restrict__ kp) {
    int n0 = nt * 64;
    int tid = threadIdx.x, w = tid >> 6, l = tid & 63;
    short* U = (short*)smem;                        // 288*72 shorts
    auto Xs = (short(*)[72])(smem + 41472);
    float* red = (float*)(smem + 50688);

    float pm = partial[tid];
    for (int o = 32; o > 0; o >>= 1) pm = fmaxf(pm, __shfl_down(pm, o));
    if (l == 0) red[w] = pm;

    short (*rfb)[72] = (short(*)[72])U;
    for (int lp = 0; lp < 5; ++lp) {
        int c = tid + lp * 256;
        if (c < 288 * 4) {
            int m = c >> 2, dq = (c & 3) * 16;
            short8 s0, s1;
            if (m < MFEAT) {
                f32x4 v0 = *(const f32x4*)&rf[(size_t)m * DK + dq];
                f32x4 v1 = *(const f32x4*)&rf[(size_t)m * DK + dq + 4];
                f32x4 v2 = *(const f32x4*)&rf[(size_t)m * DK + dq + 8];
                f32x4 v3 = *(const f32x4*)&rf[(size_t)m * DK + dq + 12];
                for (int j = 0; j < 4; ++j) {
                    s0[j] = f2bf(v0[j]); s0[4 + j] = f2bf(v1[j]);
                    s1[j] = f2bf(v2[j]); s1[4 + j] = f2bf(v3[j]);
                }
            } else {
                for (int j = 0; j < 8; ++j) { s0[j] = 0; s1[j] = 0; }
            }
            *(short8*)&rfb[m][dq] = s0;
            *(short8*)&rfb[m][dq + 8] = s1;
        }
    }
    const short* xh = isQ ? qh : kh;
    {
        int n = tid >> 2, dq = (tid & 3) * 16;
        const short* src = xh + (size_t)(n0 + n) * DMODEL + h * DK + dq;
        *(short8*)&Xs[n][dq] = *(const short8*)src;
        *(short8*)&Xs[n][dq + 8] = *(const short8*)(src + 8);
    }
    __syncthreads();
    float ks = fmaxf(fmaxf(red[0], red[1]), fmaxf(red[2], red[3]));

    int fr = l & 15, fq = (l >> 4) * 8;
    short8 xb0 = *(const short8*)&Xs[w * 16 + fr][fq];
    short8 xb1 = *(const short8*)&Xs[w * 16 + fr][32 + fq];
    f32x4 acc[18];
#pragma unroll
    for (int tr = 0; tr < 18; ++tr) acc[tr] = f32x4{0, 0, 0, 0};
#pragma unroll
    for (int tr = 0; tr < 18; ++tr) {
        short8 a0 = *(const short8*)&rfb[tr * 16 + fr][fq];
        short8 a1 = *(const short8*)&rfb[tr * 16 + fr][32 + fq];
        acc[tr] = __builtin_amdgcn_mfma_f32_16x16x32_bf16(a0, xb0, acc[tr], 0, 0, 0);
        acc[tr] = __builtin_amdgcn_mfma_f32_16x16x32_bf16(a1, xb1, acc[tr], 0, 0, 0);
    }
    __syncthreads();  // rfb reads done; U becomes kp_lds

    short (*kpl)[296] = (short(*)[296])U;
    int n_loc = w * 16 + fr;
    int n = n0 + n_loc;
    const float cnorm = 0.06131393394849658f;  // 266^-0.5
    float hval = isQ ? 0.f : (hkv[(size_t)h * NSEQ + n] - ks);
#pragma unroll
    for (int tr = 0; tr < 18; ++tr) {
        sv4 o;
        for (int j = 0; j < 4; ++j) {
            int m = tr * 16 + (l >> 4) * 4 + j;
            float val = (m < MFEAT) ? cnorm * (expf(acc[tr][j] + hval) + KERNEL_EPS) : 0.f;
            o[j] = f2bf(val);
        }
        *(sv4*)&kpl[n_loc][tr * 16 + (l >> 4) * 4] = o;
    }
    __syncthreads();
    short* outp = isQ ? qp : kp;
    for (int lp = 0; lp < 9; ++lp) {
        int c = tid + lp * 256;
        int nn = c / 36, c8 = c % 36;
        short8 v = *(const short8*)&kpl[nn][c8 * 8];
        *(short8*)&outp[((size_t)h * NSEQ + n0 + nn) * MPAD + c8 * 8] = v;
    }
}

// ---- per-chunk sums (MFMA). smem: 50688 B ----
__device__ __forceinline__ void chunksum_body(char* smem, int t, int h,
                                              const short* __restrict__ kp,
                                              const short* __restrict__ vh,
                                              short* __restrict__ KVc,
                                              float* __restrict__ Ks) {
    short* kpT = (short*)smem;                      // [m][i-swizzled], flat 288*72
    auto Vt = (short(*)[72])(smem + 41472);
    int tid = threadIdx.x;
    int w = tid >> 6, l = tid & 63;
    int fr = l & 15, fq8 = (l >> 4) * 8;
    const short* kpb = kp + ((size_t)h * NSEQ + (size_t)t * 64) * MPAD;

    for (int lp = 0; lp < 9; ++lp) {
        int c = tid + lp * 256;
        int i = c / 36, c8 = c % 36;
        short8 v = *(const short8*)&kpb[(size_t)i * MPAD + c8 * 8];
        int i8 = i >> 3, i7 = i & 7;
        for (int jj = 0; jj < 8; ++jj) {
            int m = c8 * 8 + jj;
            int ig = i8 ^ ((m >> 3) & 7);
            kpT[m * 72 + ig * 8 + i7] = v[jj];
        }
    }
    for (int lp = 0; lp < 2; ++lp) {
        int c = tid + lp * 256;
        int i = c & 63, d8 = (c >> 6) * 8;
        short8 v = *(const short8*)&vh[(size_t)(t * 64 + i) * DMODEL + h * DV + d8];
        for (int jj = 0; jj < 8; ++jj) Vt[d8 + jj][i] = v[jj];
    }
    __syncthreads();

    f32x4 acc[5][4];
#pragma unroll
    for (int tt = 0; tt < 5; ++tt)
        for (int nf = 0; nf < 4; ++nf) acc[tt][nf] = f32x4{0, 0, 0, 0};
#pragma unroll
    for (int tt = 0; tt < 5; ++tt) {
        int tr = w + tt * 4;
        if (tr < 18) {
            int row = tr * 16 + fr;
            int swz = (row >> 3) & 7;
            short8 a0 = *(const short8*)&kpT[row * 72 + (((fq8 >> 3)) ^ swz) * 8];
            short8 a1 = *(const short8*)&kpT[row * 72 + ((4 + (fq8 >> 3)) ^ swz) * 8];
            for (int nf = 0; nf < 4; ++nf) {
                short8 b0 = *(const short8*)&Vt[nf * 16 + fr][fq8];
                short8 b1 = *(const short8*)&Vt[nf * 16 + fr][32 + fq8];
                acc[tt][nf] = __builtin_amdgcn_mfma_f32_16x16x32_bf16(a0, b0, acc[tt][nf], 0, 0, 0);
                acc[tt][nf] = __builtin_amdgcn_mfma_f32_16x16x32_bf16(a1, b1, acc[tt][nf], 0, 0, 0);
            }
        }
    }
    for (int m = tid; m < MPAD; m += 256) {
        int swz = (m >> 3) & 7;
        float s = 0.f;
        for (int i8 = 0; i8 < 8; ++i8) {
            int ig = i8 ^ swz;
            for (int j = 0; j < 8; ++j) s += bf2f(kpT[m * 72 + ig * 8 + j]);
        }
        Ks[((size_t)h * NT + t) * MPAD + m] = s;
    }
    __syncthreads();
    short* kvT = kpT;
#pragma unroll
    for (int tt = 0; tt < 5; ++tt) {
        int tr = w + tt * 4;
        if (tr < 18) {
            for (int nf = 0; nf < 4; ++nf) {
                int dv = nf * 16 + fr;
                for (int j = 0; j < 4; ++j) {
                    int m = tr * 16 + (l >> 4) * 4 + j;
                    kvT[dv * 296 + m] = f2bf(acc[tt][nf][j]);
                }
            }
        }
    }
    __syncthreads();
    for (int lp = 0; lp < 9; ++lp) {
        int c = tid + lp * 256;
        int dv = c / 36, c8 = c % 36;
        short8 v = *(const short8*)&kvT[dv * 296 + c8 * 8];
        *(short8*)&KVc[(((size_t)h * NT + t) * DV + dv) * MPAD + c8 * 8] = v;
    }
}

// ---- one scan task ----
__device__ __forceinline__ void scan_task(int idx,
                                          const short* __restrict__ KVc,
                                          short* __restrict__ KVbT,
                                          float* __restrict__ Ks,
                                          float* __restrict__ Ktot) {
    const int NKV = NHEAD * DV * MPAD;
    if (idx < NKV) {
        int h = idx / (DV * MPAD);
        int rem = idx % (DV * MPAD);
        size_t base = (size_t)h * NT * DV * MPAD + rem;
        short vals[NT];
#pragma unroll
        for (int t = 0; t < NT; ++t) vals[t] = KVc[base + (size_t)t * DV * MPAD];
        float run = 0.f;
#pragma unroll
        for (int t = 0; t < NT; ++t) {
            KVbT[base + (size_t)t * DV * MPAD] = f2bf(run);
            run += bf2f(vals[t]);
        }
    } else {
        int j = idx - NKV;
        if (j < NHEAD * MPAD) {
            int h = j / MPAD, m = j % MPAD;
            size_t base = (size_t)h * NT * MPAD + m;
            float vals[NT];
#pragma unroll
            for (int t = 0; t < NT; ++t) vals[t] = Ks[base + (size_t)t * MPAD];
            float run = 0.f;
#pragma unroll
            for (int t = 0; t < NT; ++t) {
                Ks[base + (size_t)t * MPAD] = run;
                run += vals[t];
            }
            Ktot[(size_t)h * MPAD + m] = run;
        }
    }
}

// ---- phase C. smem: 58880 B ----
__device__ __forceinline__ void phasec_body(char* smem, int t, int h,
                                            const short* __restrict__ qp,
                                            const short* __restrict__ kp,
                                            const short* __restrict__ vh,
                                            const short* __restrict__ KVbT,
                                            const float* __restrict__ Ks,
                                            const float* __restrict__ Ktot,
                                            float* __restrict__ attn) {
    auto Buf = (short(*)[296])smem;
    auto Vt = (short(*)[72])(smem + 37888);
    auto Am = (short(*)[72])(smem + 47104);
    float* Ksp = (float*)(smem + 56320);
    float* Ktp = (float*)(smem + 57472);
    float* fscale_s = (float*)(smem + 58624);
    int tid = threadIdx.x;
    int w = tid >> 6, l = tid & 63;
    int fr = l & 15, fq = (l >> 4) * 8;
    const short* qpb = qp + ((size_t)h * NSEQ + (size_t)t * 64) * MPAD;
    const short* kpb = kp + ((size_t)h * NSEQ + (size_t)t * 64) * MPAD;
    const short* stb = KVbT + ((size_t)h * NT + t) * DV * MPAD;

    short8 qf[9];
#pragma unroll
    for (int ks = 0; ks < 9; ++ks)
        qf[ks] = *(const short8*)&qpb[(size_t)(w * 16 + fr) * MPAD + ks * 32 + fq];

    int srow = tid >> 2, sc4 = tid & 3;
#pragma unroll
    for (int lp = 0; lp < 9; ++lp) {
        int c = sc4 + lp * 4;
        *(short8*)&Buf[srow][c * 8] = *(const short8*)&kpb[(size_t)srow * MPAD + c * 8];
    }
    for (int lp = 0; lp < 2; ++lp) {
        int c = tid + lp * 256;
        int i = c & 63, d8 = (c >> 6) * 8;
        short8 v = *(const short8*)&vh[(size_t)(t * 64 + i) * DMODEL + h * DV + d8];
        for (int jj = 0; jj < 8; ++jj) Vt[d8 + jj][i] = v[jj];
    }
    for (int idx = tid; idx < MPAD; idx += 256) {
        Ksp[idx] = Ks[((size_t)h * NT + t) * MPAD + idx];
        Ktp[idx] = Ktot[(size_t)h * MPAD + idx];
    }
    short8 stg[9];
#pragma unroll
    for (int lp = 0; lp < 9; ++lp) {
        int c = sc4 + lp * 4;
        stg[lp] = *(const short8*)&stb[(size_t)srow * MPAD + c * 8];
    }
    __syncthreads();

    f32x4 accA[4] = {f32x4{0,0,0,0}, f32x4{0,0,0,0}, f32x4{0,0,0,0}, f32x4{0,0,0,0}};
    f32x4 accO[4] = {f32x4{0,0,0,0}, f32x4{0,0,0,0}, f32x4{0,0,0,0}, f32x4{0,0,0,0}};
#pragma unroll 3
    for (int ks = 0; ks < 9; ++ks) {
        int ko = ks * 32 + fq;
        for (int nf = 0; nf < 4; ++nf) {
            short8 bk = *(const short8*)&Buf[nf * 16 + fr][ko];
            accA[nf] = __builtin_amdgcn_mfma_f32_16x16x32_bf16(qf[ks], bk, accA[nf], 0, 0, 0);
        }
    }
    __syncthreads();
#pragma unroll
    for (int lp = 0; lp < 9; ++lp) {
        int c = sc4 + lp * 4;
        *(short8*)&Buf[srow][c * 8] = stg[lp];
    }
    for (int nf = 0; nf < 4; ++nf) {
        int col = nf * 16 + fr;
        for (int j = 0; j < 4; ++j) {
            int row = w * 16 + (l >> 4) * 4 + j;
            Am[row][col] = (col <= row) ? f2bf(accA[nf][j]) : (short)0;
        }
    }
    __syncthreads();
#pragma unroll 3
    for (int ks = 0; ks < 9; ++ks) {
        int ko = ks * 32 + fq;
        for (int nf = 0; nf < 4; ++nf) {
            short8 bs = *(const short8*)&Buf[nf * 16 + fr][ko];
            accO[nf] = __builtin_amdgcn_mfma_f32_16x16x32_bf16(qf[ks], bs, accO[nf], 0, 0, 0);
        }
    }
#pragma unroll
    for (int ks = 0; ks < 2; ++ks) {
        int ko = ks * 32 + fq;
        short8 a = *(const short8*)&Am[w * 16 + fr][ko];
        for (int nf = 0; nf < 4; ++nf) {
            short8 b = *(const short8*)&Vt[nf * 16 + fr][ko];
            accO[nf] = __builtin_amdgcn_mfma_f32_16x16x32_bf16(a, b, accO[nf], 0, 0, 0);
        }
    }
    int di = tid >> 2, dp = tid & 3;
    float dc = 0.f, df = 0.f;
    {
        const short* amrow = &Am[di][dp * 16];
        short8 s0 = *(const short8*)amrow;
        short8 s1 = *(const short8*)(amrow + 8);
        for (int j2 = 0; j2 < 8; ++j2) dc += bf2f(s0[j2]) + bf2f(s1[j2]);
    }
#pragma unroll
    for (int c8 = 0; c8 < 9; ++c8) {
        int m = dp * 72 + c8 * 8;
        short8 qv = *(const short8*)&qpb[(size_t)di * MPAD + m];
        for (int j2 = 0; j2 < 8; ++j2) {
            float qq = bf2f(qv[j2]);
            dc += qq * Ksp[m + j2];
            df += qq * Ktp[m + j2];
        }
    }
    dc += __shfl_xor(dc, 1); dc += __shfl_xor(dc, 2);
    df += __shfl_xor(df, 1); df += __shfl_xor(df, 2);
    if (dp == 0) {
        float dst = df;
        if (fabsf(dst) <= NORM_STAB) dst += 2.f * NORM_STAB;
        fscale_s[di] = (1.f / dc) / dst;
    }
    __syncthreads();
    for (int nf = 0; nf < 4; ++nf) {
        int col = nf * 16 + fr;
        for (int j = 0; j < 4; ++j) {
            int row = w * 16 + (l >> 4) * 4 + j;
            attn[((size_t)t * 64 + row) * DMODEL + h * DV + col] = accO[nf][j] * fscale_s[row];
        }
    }
}

// ---- final GEMM tile with bias + residual. smem: 10240 B ----
__device__ __forceinline__ void fgemm_body(char* smem, int bx, int by,
                                           const float* __restrict__ A,
                                           const float* __restrict__ B,
                                           float* __restrict__ C,
                                           const float* __restrict__ bias,
                                           const float* __restrict__ residual) {
    auto As = (short(*)[40])smem;
    auto Bs = (short(*)[40])(smem + 5120);
    int bm = by * 64, bn = bx * 64;
    int tid = threadIdx.x;
    int wid = tid >> 6, lane = tid & 63;
    f32x4 acc[4] = {f32x4{0,0,0,0}, f32x4{0,0,0,0}, f32x4{0,0,0,0}, f32x4{0,0,0,0}};
    int ar = tid >> 2, akq = tid & 3;
    int bkk = tid >> 3, bng = tid & 7;
    for (int k0 = 0; k0 < DMODEL; k0 += 32) {
        {
            const float* src = A + (size_t)(bm + ar) * DMODEL + k0 + akq * 8;
            f32x4 v0 = *(const f32x4*)src;
            f32x4 v1 = *(const f32x4*)(src + 4);
            short8 sv;
            for (int j = 0; j < 4; ++j) { sv[j] = f2bf(v0[j]); sv[4 + j] = f2bf(v1[j]); }
            *(short8*)&As[ar][akq * 8] = sv;
        }
        {
            const float* src = B + (size_t)(k0 + bkk) * DMODEL + bn + bng * 8;
            f32x4 v0 = *(const f32x4*)src;
            f32x4 v1 = *(const f32x4*)(src + 4);
            for (int j = 0; j < 4; ++j) {
                Bs[bng * 8 + j][bkk] = f2bf(v0[j]);
                Bs[bng * 8 + 4 + j][bkk] = f2bf(v1[j]);
            }
        }
        __syncthreads();
        int row = wid * 16 + (lane & 15);
        int koff = (lane >> 4) * 8;
        short8 a = *(const short8*)&As[row][koff];
        for (int nf = 0; nf < 4; ++nf) {
            int col = nf * 16 + (lane & 15);
            short8 b = *(const short8*)&Bs[col][koff];
            acc[nf] = __builtin_amdgcn_mfma_f32_16x16x32_bf16(a, b, acc[nf], 0, 0, 0);
        }
        __syncthreads();
    }
    for (int nf = 0; nf < 4; ++nf) {
        int col = bn + nf * 16 + (lane & 15);
        for (int j = 0; j < 4; ++j) {
            int row = bm + wid * 16 + (lane >> 4) * 4 + j;
            C[(size_t)row * DMODEL + col] =
                acc[nf][j] + bias[col] + residual[(size_t)row * DMODEL + col];
        }
    }
}

// ============ cooperative mega-kernel: all phases, one dispatch ============
__global__ __launch_bounds__(256) void mega_kernel(
    const float* qx, const float* kx, const float* vx,
    const float* Wq, const float* Wk, const float* Wv,
    const float* Wfc, const float* bfc,
    const float* gamma, const float* beta, const float* rf,
    float* out,
    short* qh, short* kh, short* vh,
    short* qp, short* kp, short* KVc, short* KVbT,
    float* Ks, float* Ktot, float* hk, float* partial, float* attn) {
    cg::grid_group grid = cg::this_grid();
    __shared__ __align__(16) char smem[58880];
    int bid = blockIdx.x;
    int tid = threadIdx.x;

    // P0: QKV (768 tiles over 512 blocks)
    for (int tile = bid; tile < 768; tile += 512) {
        int z = tile >> 8, rem = tile & 255;
        int by = rem >> 3, bx = rem & 7;
        qkv_body(smem, bx, by, z, qx, kx, vx, Wq, Wk, Wv, gamma, beta,
                 qh, kh, vh, hk, partial);
        __syncthreads();
    }
    grid.sync();
    // P1: feature maps (512 tiles, 1:1)
    {
        int nt = bid & 31, h = (bid >> 5) & 7, isQ = bid >> 8;
        feat_body(smem, nt, h, isQ, qh, kh, rf, hk, partial, qp, kp);
    }
    grid.sync();
    // P2: chunk sums (256 tiles)
    if (bid < 256) chunksum_body(smem, bid & 31, bid >> 5, kp, vh, KVc, Ks);
    grid.sync();
    // P3: scans (149760 tasks, grid-strided)
    {
        const int total = NHEAD * DV * MPAD + NHEAD * MPAD;
        for (int idx = bid * 256 + tid; idx < total; idx += 512 * 256)
            scan_task(idx, KVc, KVbT, Ks, Ktot);
    }
    grid.sync();
    // P4: phase C (256 tiles)
    if (bid < 256) phasec_body(smem, bid & 31, bid >> 5, qp, kp, vh, KVbT, Ks, Ktot, attn);
    grid.sync();
    // P5: output GEMM (256 tiles)
    if (bid < 256) fgemm_body(smem, bid & 7, bid >> 3, attn, Wfc, out, bfc, qx);
}

// ============ fallback standalone kernels (same bodies) ============
__global__ __launch_bounds__(256) void qkv_kernel(const float* qx, const float* kx,
                                                  const float* vx, const float* Wq,
                                                  const float* Wk, const float* Wv,
                                                  const float* gamma, const float* beta,
                                                  short* qh, short* kh, short* vh,
                                                  float* hk, float* partial) {
    __shared__ __align__(16) char smem[10256];
    qkv_body(smem, blockIdx.x, blockIdx.y, blockIdx.z, qx, kx, vx, Wq, Wk, Wv,
             gamma, beta, qh, kh, vh, hk, partial);
}
__global__ __launch_bounds__(256) void feat_kernel(const short* qh, const short* kh,
                                                   const float* rf, const float* hkv,
                                                   const float* partial,
                                                   short* qp, short* kp) {
    __shared__ __align__(16) char smem[50704];
    feat_body(smem, blockIdx.x, blockIdx.y, blockIdx.z, qh, kh, rf, hkv, partial, qp, kp);
}
__global__ __launch_bounds__(256) void chunksum_kernel(const short* kp, const short* vh,
                                                       short* KVc, float* Ks) {
    __shared__ __align__(16) char smem[50688];
    chunksum_body(smem, blockIdx.x, blockIdx.y, kp, vh, KVc, Ks);
}
__global__ __launch_bounds__(256) void scan_kernel(const short* KVc, short* KVbT,
                                                   float* Ks, float* Ktot) {
    scan_task(blockIdx.x * 256 + threadIdx.x, KVc, KVbT, Ks, Ktot);
}
__global__ __launch_bounds__(256) void phasec_kernel(const short* qp, const short* kp,
                                                     const short* vh, const short* KVbT,
                                                     const float* Ks, const float* Ktot,
                                                     float* attn) {
    __shared__ __align__(16) char smem[58880];
    phasec_body(smem, blockIdx.x, blockIdx.y, qp, kp, vh, KVbT, Ks, Ktot, attn);
}
__global__ __launch_bounds__(256) void fgemm_kernel(const float* A, const float* B, float* C,
                                                    const float* bias, const float* residual) {
    __shared__ __align__(16) char smem[10240];
    fgemm_body(smem, blockIdx.x, blockIdx.y, A, B, C, bias, residual);
}

extern "C" void kernel_launch(void* const* d_in, const int* in_sizes, int n_in,
                              void* d_out, int out_size, void* d_ws, size_t ws_size,
                              hipStream_t stream) {
    const float* q = (const float*)d_in[0];
    const float* k = (const float*)d_in[1];
    const float* v = (const float*)d_in[2];
    const float* Wq = (const float*)d_in[3];
    const float* Wk = (const float*)d_in[4];
    const float* Wv = (const float*)d_in[5];
    const float* Wfc = (const float*)d_in[6];
    const float* bfc = (const float*)d_in[7];
    const float* gamma = (const float*)d_in[8];
    const float* beta = (const float*)d_in[9];
    const float* rf = (const float*)d_in[10];
    float* out = (float*)d_out;

    float* ws = (float*)d_ws;
    float* attn = ws;                                      // fp32 2048*512
    short* qh = (short*)(attn + (size_t)NSEQ * DMODEL);    // bf16 2048*512
    short* kh = qh + (size_t)NSEQ * DMODEL;
    short* vhb = kh + (size_t)NSEQ * DMODEL;
    short* qp = vhb + (size_t)NSEQ * DMODEL;               // bf16 8*2048*288
    short* kp = qp + (size_t)NHEAD * NSEQ * MPAD;
    short* KVc = kp + (size_t)NHEAD * NSEQ * MPAD;         // bf16 8*32*64*288
    short* KVbT = KVc + (size_t)NHEAD * NT * DV * MPAD;
    float* Ks = (float*)(KVbT + (size_t)NHEAD * NT * DV * MPAD);   // fp32 8*32*288
    float* Ktot = Ks + (size_t)NHEAD * NT * MPAD;
    float* hk = Ktot + (size_t)NHEAD * MPAD;               // 8*2048
    float* partial = hk + (size_t)NHEAD * NSEQ;            // 256

    void* args[] = {(void*)&q, (void*)&k, (void*)&v, (void*)&Wq, (void*)&Wk, (void*)&Wv,
                    (void*)&Wfc, (void*)&bfc, (void*)&gamma, (void*)&beta, (void*)&rf,
                    (void*)&out, (void*)&qh, (void*)&kh, (void*)&vhb, (void*)&qp,
                    (void*)&kp, (void*)&KVc, (void*)&KVbT, (void*)&Ks, (void*)&Ktot,
                    (void*)&hk, (void*)&partial, (void*)&attn};
    hipError_t err = hipLaunchCooperativeKernel((void*)mega_kernel, dim3(512, 1, 1),
                                                dim3(256, 1, 1), args, 0, stream);
    if (err != hipSuccess) {
        (void)hipGetLastError();  // clear; fall back to 6-kernel pipeline
        dim3 gq(DMODEL / 64, NSEQ / 64, 3);
        qkv_kernel<<<gq, 256, 0, stream>>>(q, k, v, Wq, Wk, Wv, gamma, beta,
                                           qh, kh, vhb, hk, partial);
        dim3 gf(NT, NHEAD, 2);
        feat_kernel<<<gf, 256, 0, stream>>>(qh, kh, rf, hk, partial, qp, kp);
        dim3 ga(NT, NHEAD);
        chunksum_kernel<<<ga, 256, 0, stream>>>(kp, vhb, KVc, Ks);
        int scan_threads = NHEAD * DV * MPAD + NHEAD * MPAD;
        scan_kernel<<<(scan_threads + 255) / 256, 256, 0, stream>>>(KVc, KVbT, Ks, Ktot);
        dim3 gc(NT, NHEAD);
        phasec_kernel<<<gc, 256, 0, stream>>>(qp, kp, vhb, KVbT, Ks, Ktot, attn);
        dim3 g(DMODEL / 64, NSEQ / 64);
        fgemm_kernel<<<g, 256, 0, stream>>>(attn, Wfc, out, bfc, q);
    }
}

// Round 12
// 91.467 us; speedup vs baseline: 4.2242x; 4.2242x over previous
//
#include <hip/hip_runtime.h>
#include <math.h>

#define DMODEL 512
#define NSEQ 2048
#define NHEAD 8
#define DK 64
#define DV 64
#define MFEAT 266
#define MPAD 288        // padded feature dim for bf16 MFMA (zero tail), mult of 32
#define NT 32           // number of chunks (chunk = 64)
#define LN_EPS 1e-6f
#define KERNEL_EPS 1e-4f
#define NORM_STAB 1e-6f
#define SCALE 0.21022410381342863f  // 512^-0.25

typedef __attribute__((ext_vector_type(8))) short short8;
typedef __attribute__((ext_vector_type(4))) short sv4;
typedef __attribute__((ext_vector_type(4))) float f32x4;

__device__ inline short f2bf(float f) {
    unsigned u = __builtin_bit_cast(unsigned, f);
    unsigned r = (u + 0x7fff + ((u >> 16) & 1)) >> 16;
    return (short)r;
}
__device__ inline float bf2f(short s) {
    unsigned u = ((unsigned)(unsigned short)s) << 16;
    return __builtin_bit_cast(float, u);
}

// ---------------- fused QKV bf16 MFMA GEMM; z=0 computes+applies LN inline; z=1 emits h_k ----------------
__global__ __launch_bounds__(256) void qkv_kernel(const float* __restrict__ qx,
                                                  const float* __restrict__ kx,
                                                  const float* __restrict__ vx,
                                                  const float* __restrict__ Wq,
                                                  const float* __restrict__ Wk,
                                                  const float* __restrict__ Wv,
                                                  const float* __restrict__ gamma,
                                                  const float* __restrict__ beta,
                                                  short* __restrict__ qh,
                                                  short* __restrict__ kh,
                                                  short* __restrict__ vh,
                                                  float* __restrict__ hk,
                                                  float* __restrict__ partial) {
    int z = blockIdx.z;
    const float* A = (z == 0) ? qx : (z == 1) ? kx : vx;
    const float* B = (z == 0) ? Wq : (z == 1) ? Wk : Wv;
    short* C = (z == 0) ? qh : (z == 1) ? kh : vh;
    float scale = (z == 2) ? 1.f : SCALE;

    __shared__ short As[64][40];
    __shared__ short Bs[64][40];
    int bm = blockIdx.y * 64, bn = blockIdx.x * 64;
    int tid = threadIdx.x;
    int wid = tid >> 6, lane = tid & 63;
    f32x4 acc[4] = {f32x4{0,0,0,0}, f32x4{0,0,0,0}, f32x4{0,0,0,0}, f32x4{0,0,0,0}};
    int ar = tid >> 2, akq = tid & 3;
    int bkk = tid >> 3, bng = tid & 7;
    float lnm = 0.f, lnr = 0.f;
    if (z == 0) {
        // per-quad LN stats for row bm+ar (4 threads per row, contiguous lanes)
        const float* xr = qx + (size_t)(bm + ar) * DMODEL + akq * 128;
        float s = 0.f, ss = 0.f;
#pragma unroll 4
        for (int i = 0; i < 128; i += 4) {
            f32x4 vv = *(const f32x4*)(xr + i);
            s += vv[0] + vv[1] + vv[2] + vv[3];
            ss += vv[0]*vv[0] + vv[1]*vv[1] + vv[2]*vv[2] + vv[3]*vv[3];
        }
        s += __shfl_xor(s, 1); s += __shfl_xor(s, 2);
        ss += __shfl_xor(ss, 1); ss += __shfl_xor(ss, 2);
        float m = s / (float)DMODEL;
        float var = ss / (float)DMODEL - m * m;
        lnm = m;
        lnr = rsqrtf(var + LN_EPS);
    }
    for (int k0 = 0; k0 < DMODEL; k0 += 32) {
        {
            const float* src = A + (size_t)(bm + ar) * DMODEL + k0 + akq * 8;
            f32x4 v0 = *(const f32x4*)src;
            f32x4 v1 = *(const f32x4*)(src + 4);
            short8 sv;
            if (z == 0) {
                f32x4 g0 = *(const f32x4*)&gamma[k0 + akq * 8];
                f32x4 g1 = *(const f32x4*)&gamma[k0 + akq * 8 + 4];
                f32x4 bb0 = *(const f32x4*)&beta[k0 + akq * 8];
                f32x4 bb1 = *(const f32x4*)&beta[k0 + akq * 8 + 4];
                for (int j = 0; j < 4; ++j) {
                    sv[j] = f2bf((v0[j] - lnm) * lnr * g0[j] + bb0[j]);
                    sv[4 + j] = f2bf((v1[j] - lnm) * lnr * g1[j] + bb1[j]);
                }
            } else {
                for (int j = 0; j < 4; ++j) { sv[j] = f2bf(v0[j]); sv[4 + j] = f2bf(v1[j]); }
            }
            *(short8*)&As[ar][akq * 8] = sv;
        }
        {
            const float* src = B + (size_t)(k0 + bkk) * DMODEL + bn + bng * 8;
            f32x4 v0 = *(const f32x4*)src;
            f32x4 v1 = *(const f32x4*)(src + 4);
            for (int j = 0; j < 4; ++j) {
                Bs[bng * 8 + j][bkk] = f2bf(v0[j] * scale);
                Bs[bng * 8 + 4 + j][bkk] = f2bf(v1[j] * scale);
            }
        }
        __syncthreads();
        int row = wid * 16 + (lane & 15);
        int koff = (lane >> 4) * 8;
        short8 a = *(const short8*)&As[row][koff];
        for (int nf = 0; nf < 4; ++nf) {
            int col = nf * 16 + (lane & 15);
            short8 b = *(const short8*)&Bs[col][koff];
            acc[nf] = __builtin_amdgcn_mfma_f32_16x16x32_bf16(a, b, acc[nf], 0, 0, 0);
        }
        __syncthreads();
    }
    for (int nf = 0; nf < 4; ++nf) {
        int col = bn + nf * 16 + (lane & 15);
        for (int j = 0; j < 4; ++j) {
            int row = bm + wid * 16 + (lane >> 4) * 4 + j;
            C[(size_t)row * DMODEL + col] = f2bf(acc[nf][j]);
        }
    }
    if (z == 1) {
        __shared__ float bmax[4];
        float hvmax = -1e30f;
        for (int j = 0; j < 4; ++j) {
            float ss = 0.f;
            for (int nf = 0; nf < 4; ++nf) ss += acc[nf][j] * acc[nf][j];
            for (int o = 1; o < 16; o <<= 1) ss += __shfl_xor(ss, o);
            float hv = -0.5f * ss;
            int row = bm + wid * 16 + (lane >> 4) * 4 + j;
            if ((lane & 15) == 0) hk[(size_t)blockIdx.x * NSEQ + row] = hv;
            hvmax = fmaxf(hvmax, hv);
        }
        for (int o = 32; o > 0; o >>= 1) hvmax = fmaxf(hvmax, __shfl_down(hvmax, o));
        if (lane == 0) bmax[wid] = hvmax;
        __syncthreads();
        if (tid == 0)
            partial[blockIdx.y * 8 + blockIdx.x] =
                fmaxf(fmaxf(bmax[0], bmax[1]), fmaxf(bmax[2], bmax[3]));
    }
}

// ---------------- MFMA random feature maps -> bf16 [h][n][MPAD]; grid (nt, h, isQ) ----------------
__global__ __launch_bounds__(256) void feat_kernel(const short* __restrict__ qh,
                                                   const short* __restrict__ kh,
                                                   const float* __restrict__ rf,
                                                   const float* __restrict__ hkv,
                                                   const float* __restrict__ partial,
                                                   short* __restrict__ qp,
                                                   short* __restrict__ kp) {
    int nt = blockIdx.x, h = blockIdx.y, isQ = blockIdx.z;
    int n0 = nt * 64;
    int tid = threadIdx.x, w = tid >> 6, l = tid & 63;
    __shared__ short U[288 * 72];   // union: rfb[288][72] then kp_lds[64][296]
    __shared__ short Xs[64][72];
    __shared__ float red[4];

    // inline kstab reduce (partial[256] written by qkv z=1)
    float pm = partial[tid];
    for (int o = 32; o > 0; o >>= 1) pm = fmaxf(pm, __shfl_down(pm, o));
    if (l == 0) red[w] = pm;

    // stage rf -> bf16 rfb[m][d] (zero for m>=MFEAT)
    short (*rfb)[72] = (short(*)[72])U;
    for (int lp = 0; lp < 5; ++lp) {
        int c = tid + lp * 256;
        if (c < 288 * 4) {
            int m = c >> 2, dq = (c & 3) * 16;
            short8 s0, s1;
            if (m < MFEAT) {
                f32x4 v0 = *(const f32x4*)&rf[(size_t)m * DK + dq];
                f32x4 v1 = *(const f32x4*)&rf[(size_t)m * DK + dq + 4];
                f32x4 v2 = *(const f32x4*)&rf[(size_t)m * DK + dq + 8];
                f32x4 v3 = *(const f32x4*)&rf[(size_t)m * DK + dq + 12];
                for (int j = 0; j < 4; ++j) {
                    s0[j] = f2bf(v0[j]); s0[4 + j] = f2bf(v1[j]);
                    s1[j] = f2bf(v2[j]); s1[4 + j] = f2bf(v3[j]);
                }
            } else {
                for (int j = 0; j < 8; ++j) { s0[j] = 0; s1[j] = 0; }
            }
            *(short8*)&rfb[m][dq] = s0;
            *(short8*)&rfb[m][dq + 8] = s1;
        }
    }
    // stage X chunk (bf16) -> Xs[n][d]
    const short* xh = isQ ? qh : kh;
    {
        int n = tid >> 2, dq = (tid & 3) * 16;
        const short* src = xh + (size_t)(n0 + n) * DMODEL + h * DK + dq;
        *(short8*)&Xs[n][dq] = *(const short8*)src;
        *(short8*)&Xs[n][dq + 8] = *(const short8*)(src + 8);
    }
    __syncthreads();
    float ks = fmaxf(fmaxf(red[0], red[1]), fmaxf(red[2], red[3]));

    // proj MFMA: C[m][n] = sum_d rfb[m][d] * Xs[n][d]; wave w owns n-tile w
    int fr = l & 15, fq = (l >> 4) * 8;
    short8 xb0 = *(const short8*)&Xs[w * 16 + fr][fq];
    short8 xb1 = *(const short8*)&Xs[w * 16 + fr][32 + fq];
    f32x4 acc[18];
#pragma unroll
    for (int tr = 0; tr < 18; ++tr) acc[tr] = f32x4{0, 0, 0, 0};
#pragma unroll
    for (int tr = 0; tr < 18; ++tr) {
        short8 a0 = *(const short8*)&rfb[tr * 16 + fr][fq];
        short8 a1 = *(const short8*)&rfb[tr * 16 + fr][32 + fq];
        acc[tr] = __builtin_amdgcn_mfma_f32_16x16x32_bf16(a0, xb0, acc[tr], 0, 0, 0);
        acc[tr] = __builtin_amdgcn_mfma_f32_16x16x32_bf16(a1, xb1, acc[tr], 0, 0, 0);
    }
    __syncthreads();  // all waves done reading rfb; U becomes kp_lds

    short (*kpl)[296] = (short(*)[296])U;
    int n_loc = w * 16 + fr;
    int n = n0 + n_loc;
    const float cnorm = 0.06131393394849658f;  // 266^-0.5
    float hval = isQ ? 0.f : (hkv[(size_t)h * NSEQ + n] - ks);
#pragma unroll
    for (int tr = 0; tr < 18; ++tr) {
        sv4 o;
        for (int j = 0; j < 4; ++j) {
            int m = tr * 16 + (l >> 4) * 4 + j;
            float val = (m < MFEAT) ? cnorm * (expf(acc[tr][j] + hval) + KERNEL_EPS) : 0.f;
            o[j] = f2bf(val);
        }
        *(sv4*)&kpl[n_loc][tr * 16 + (l >> 4) * 4] = o;
    }
    __syncthreads();
    // coalesced copy kp_lds rows -> HBM
    short* outp = isQ ? qp : kp;
    for (int lp = 0; lp < 9; ++lp) {
        int c = tid + lp * 256;      // 64 rows * 36 chunks
        int nn = c / 36, c8 = c % 36;
        short8 v = *(const short8*)&kpl[nn][c8 * 8];
        *(short8*)&outp[((size_t)h * NSEQ + n0 + nn) * MPAD + c8 * 8] = v;
    }
}

// ---------------- phase A (MFMA): per-chunk sums -> bf16 KVc[(h,t,dv)][m], fp32 Ks[(h,t)][m] ----------------
__global__ __launch_bounds__(256) void chunksum_kernel(const short* __restrict__ kp,
                                                       const short* __restrict__ vh,
                                                       short* __restrict__ KVc,
                                                       float* __restrict__ Ks) {
    int t = blockIdx.x, h = blockIdx.y;
    __shared__ short kpT[288 * 72];   // [m][i-swizzled], stride 72 shorts (144B); 41.5KB
    __shared__ short Vt[64][72];      // [dv][i]
    int tid = threadIdx.x;
    int w = tid >> 6, l = tid & 63;
    int fr = l & 15, fq8 = (l >> 4) * 8;
    const short* kpb = kp + ((size_t)h * NSEQ + (size_t)t * 64) * MPAD;

    // stage kp^T: read rows coalesced, scatter to swizzled columns
    for (int lp = 0; lp < 9; ++lp) {
        int c = tid + lp * 256;       // 2304 = 64 i * 36 m-chunks
        int i = c / 36, c8 = c % 36;
        short8 v = *(const short8*)&kpb[(size_t)i * MPAD + c8 * 8];
        int i8 = i >> 3, i7 = i & 7;
        for (int jj = 0; jj < 8; ++jj) {
            int m = c8 * 8 + jj;
            int ig = i8 ^ ((m >> 3) & 7);
            kpT[m * 72 + ig * 8 + i7] = v[jj];
        }
    }
    // stage V^T
    for (int lp = 0; lp < 2; ++lp) {
        int c = tid + lp * 256;       // 512 = 64 i * 8 d-chunks
        int i = c & 63, d8 = (c >> 6) * 8;
        short8 v = *(const short8*)&vh[(size_t)(t * 64 + i) * DMODEL + h * DV + d8];
        for (int jj = 0; jj < 8; ++jj) Vt[d8 + jj][i] = v[jj];
    }
    __syncthreads();

    // D[m][dv] = sum_i kp^T[m][i] * V[i][dv]; wave w owns m-tiles {w, w+4, ...}
    f32x4 acc[5][4];
#pragma unroll
    for (int tt = 0; tt < 5; ++tt)
        for (int nf = 0; nf < 4; ++nf) acc[tt][nf] = f32x4{0, 0, 0, 0};
#pragma unroll
    for (int tt = 0; tt < 5; ++tt) {
        int tr = w + tt * 4;
        if (tr < 18) {
            int row = tr * 16 + fr;
            int swz = (row >> 3) & 7;
            short8 a0 = *(const short8*)&kpT[row * 72 + (((fq8 >> 3)) ^ swz) * 8];
            short8 a1 = *(const short8*)&kpT[row * 72 + ((4 + (fq8 >> 3)) ^ swz) * 8];
            for (int nf = 0; nf < 4; ++nf) {
                short8 b0 = *(const short8*)&Vt[nf * 16 + fr][fq8];
                short8 b1 = *(const short8*)&Vt[nf * 16 + fr][32 + fq8];
                acc[tt][nf] = __builtin_amdgcn_mfma_f32_16x16x32_bf16(a0, b0, acc[tt][nf], 0, 0, 0);
                acc[tt][nf] = __builtin_amdgcn_mfma_f32_16x16x32_bf16(a1, b1, acc[tt][nf], 0, 0, 0);
            }
        }
    }
    // Ks[m] = sum_i kp^T[m][i]
    for (int m = tid; m < MPAD; m += 256) {
        int swz = (m >> 3) & 7;
        float s = 0.f;
        for (int i8 = 0; i8 < 8; ++i8) {
            int ig = i8 ^ swz;
            for (int j = 0; j < 8; ++j) s += bf2f(kpT[m * 72 + ig * 8 + j]);
        }
        Ks[((size_t)h * NT + t) * MPAD + m] = s;
    }
    __syncthreads();  // kpT reads done; overlay kvT
    short* kvT = kpT; // [64 dv][296 m] = 37.9KB <= 41.5KB
#pragma unroll
    for (int tt = 0; tt < 5; ++tt) {
        int tr = w + tt * 4;
        if (tr < 18) {
            for (int nf = 0; nf < 4; ++nf) {
                int dv = nf * 16 + fr;
                for (int j = 0; j < 4; ++j) {
                    int m = tr * 16 + (l >> 4) * 4 + j;
                    kvT[dv * 296 + m] = f2bf(acc[tt][nf][j]);
                }
            }
        }
    }
    __syncthreads();
    // coalesced KVc store
    for (int lp = 0; lp < 9; ++lp) {
        int c = tid + lp * 256;       // 2304 = 64 dv * 36
        int dv = c / 36, c8 = c % 36;
        short8 v = *(const short8*)&kvT[dv * 296 + c8 * 8];
        *(short8*)&KVc[(((size_t)h * NT + t) * DV + dv) * MPAD + c8 * 8] = v;
    }
}

// ---------------- fused exclusive chunk-scans, batched loads (all 32 independent) ----------------
__global__ __launch_bounds__(256) void scan_kernel(const short* __restrict__ KVc,
                                                   short* __restrict__ KVbT,
                                                   float* __restrict__ Ks,
                                                   float* __restrict__ Ktot) {
    int idx = blockIdx.x * 256 + threadIdx.x;
    const int NKV = NHEAD * DV * MPAD;       // 147456
    if (idx < NKV) {
        int h = idx / (DV * MPAD);
        int rem = idx % (DV * MPAD);
        size_t base = (size_t)h * NT * DV * MPAD + rem;
        short vals[NT];
#pragma unroll
        for (int t = 0; t < NT; ++t) vals[t] = KVc[base + (size_t)t * DV * MPAD];
        float run = 0.f;
#pragma unroll
        for (int t = 0; t < NT; ++t) {
            KVbT[base + (size_t)t * DV * MPAD] = f2bf(run);
            run += bf2f(vals[t]);
        }
    } else {
        int j = idx - NKV;
        if (j < NHEAD * MPAD) {
            int h = j / MPAD, m = j % MPAD;
            size_t base = (size_t)h * NT * MPAD + m;
            float vals[NT];
#pragma unroll
            for (int t = 0; t < NT; ++t) vals[t] = Ks[base + (size_t)t * MPAD];
            float run = 0.f;
#pragma unroll
            for (int t = 0; t < NT; ++t) {
                Ks[base + (size_t)t * MPAD] = run;
                run += vals[t];
            }
            Ktot[(size_t)h * MPAD + m] = run;
        }
    }
}

// ---------------- phase C: MFMA intra+inter+denominators; grid (t, h); S^T async-staged; bf16 out ----------------
__global__ __launch_bounds__(256) void phasec_kernel(const short* __restrict__ qp,
                                                     const short* __restrict__ kp,
                                                     const short* __restrict__ vh,
                                                     const short* __restrict__ KVbT,
                                                     const float* __restrict__ Ks,
                                                     const float* __restrict__ Ktot,
                                                     short* __restrict__ attn) {
    int t = blockIdx.x, h = blockIdx.y;
    __shared__ short Buf[64][296];   // Kp (QK^T phase) then St (inter phase)
    __shared__ short Vt[64][72];     // [dv][i]
    __shared__ short Am[64][72];     // masked A, bf16
    __shared__ float Ksp[MPAD], Ktp[MPAD];
    __shared__ float fscale_s[64];
    int tid = threadIdx.x;
    int w = tid >> 6, l = tid & 63;
    int fr = l & 15, fq = (l >> 4) * 8;
    const short* qpb = qp + ((size_t)h * NSEQ + (size_t)t * 64) * MPAD;
    const short* kpb = kp + ((size_t)h * NSEQ + (size_t)t * 64) * MPAD;
    const short* stb = KVbT + ((size_t)h * NT + t) * DV * MPAD;

    short8 qf[9];
#pragma unroll
    for (int ks = 0; ks < 9; ++ks)
        qf[ks] = *(const short8*)&qpb[(size_t)(w * 16 + fr) * MPAD + ks * 32 + fq];

    int srow = tid >> 2, sc4 = tid & 3;
#pragma unroll
    for (int lp = 0; lp < 9; ++lp) {
        int c = sc4 + lp * 4;
        *(short8*)&Buf[srow][c * 8] = *(const short8*)&kpb[(size_t)srow * MPAD + c * 8];
    }
    // stage Vt via row reads + LDS transpose
    for (int lp = 0; lp < 2; ++lp) {
        int c = tid + lp * 256;
        int i = c & 63, d8 = (c >> 6) * 8;
        short8 v = *(const short8*)&vh[(size_t)(t * 64 + i) * DMODEL + h * DV + d8];
        for (int jj = 0; jj < 8; ++jj) Vt[d8 + jj][i] = v[jj];
    }
    for (int idx = tid; idx < MPAD; idx += 256) {
        Ksp[idx] = Ks[((size_t)h * NT + t) * MPAD + idx];
        Ktp[idx] = Ktot[(size_t)h * MPAD + idx];
    }
    // async-issue S^T loads; latency hides under QK^T MFMAs
    short8 stg[9];
#pragma unroll
    for (int lp = 0; lp < 9; ++lp) {
        int c = sc4 + lp * 4;
        stg[lp] = *(const short8*)&stb[(size_t)srow * MPAD + c * 8];
    }
    __syncthreads();

    f32x4 accA[4] = {f32x4{0,0,0,0}, f32x4{0,0,0,0}, f32x4{0,0,0,0}, f32x4{0,0,0,0}};
    f32x4 accO[4] = {f32x4{0,0,0,0}, f32x4{0,0,0,0}, f32x4{0,0,0,0}, f32x4{0,0,0,0}};
#pragma unroll 3
    for (int ks = 0; ks < 9; ++ks) {
        int ko = ks * 32 + fq;
        for (int nf = 0; nf < 4; ++nf) {
            short8 bk = *(const short8*)&Buf[nf * 16 + fr][ko];
            accA[nf] = __builtin_amdgcn_mfma_f32_16x16x32_bf16(qf[ks], bk, accA[nf], 0, 0, 0);
        }
    }
    __syncthreads();
#pragma unroll
    for (int lp = 0; lp < 9; ++lp) {
        int c = sc4 + lp * 4;
        *(short8*)&Buf[srow][c * 8] = stg[lp];
    }
    for (int nf = 0; nf < 4; ++nf) {
        int col = nf * 16 + fr;
        for (int j = 0; j < 4; ++j) {
            int row = w * 16 + (l >> 4) * 4 + j;
            Am[row][col] = (col <= row) ? f2bf(accA[nf][j]) : (short)0;
        }
    }
    __syncthreads();
#pragma unroll 3
    for (int ks = 0; ks < 9; ++ks) {
        int ko = ks * 32 + fq;
        for (int nf = 0; nf < 4; ++nf) {
            short8 bs = *(const short8*)&Buf[nf * 16 + fr][ko];
            accO[nf] = __builtin_amdgcn_mfma_f32_16x16x32_bf16(qf[ks], bs, accO[nf], 0, 0, 0);
        }
    }
#pragma unroll
    for (int ks = 0; ks < 2; ++ks) {
        int ko = ks * 32 + fq;
        short8 a = *(const short8*)&Am[w * 16 + fr][ko];
        for (int nf = 0; nf < 4; ++nf) {
            short8 b = *(const short8*)&Vt[nf * 16 + fr][ko];
            accO[nf] = __builtin_amdgcn_mfma_f32_16x16x32_bf16(a, b, accO[nf], 0, 0, 0);
        }
    }
    int di = tid >> 2, dp = tid & 3;
    float dc = 0.f, df = 0.f;
    {
        const short* amrow = &Am[di][dp * 16];
        short8 s0 = *(const short8*)amrow;
        short8 s1 = *(const short8*)(amrow + 8);
        for (int j2 = 0; j2 < 8; ++j2) dc += bf2f(s0[j2]) + bf2f(s1[j2]);
    }
#pragma unroll
    for (int c8 = 0; c8 < 9; ++c8) {
        int m = dp * 72 + c8 * 8;
        short8 qv = *(const short8*)&qpb[(size_t)di * MPAD + m];
        for (int j2 = 0; j2 < 8; ++j2) {
            float qq = bf2f(qv[j2]);
            dc += qq * Ksp[m + j2];
            df += qq * Ktp[m + j2];
        }
    }
    dc += __shfl_xor(dc, 1); dc += __shfl_xor(dc, 2);
    df += __shfl_xor(df, 1); df += __shfl_xor(df, 2);
    if (dp == 0) {
        float dst = df;
        if (fabsf(dst) <= NORM_STAB) dst += 2.f * NORM_STAB;
        fscale_s[di] = (1.f / dc) / dst;
    }
    __syncthreads();
    for (int nf = 0; nf < 4; ++nf) {
        int col = nf * 16 + fr;
        for (int j = 0; j < 4; ++j) {
            int row = w * 16 + (l >> 4) * 4 + j;
            attn[((size_t)t * 64 + row) * DMODEL + h * DV + col] =
                f2bf(accO[nf][j] * fscale_s[row]);
        }
    }
}

// ---------------- final GEMM with bias + residual (A is bf16) ----------------
__global__ __launch_bounds__(256) void fgemm_kernel(const short* __restrict__ A,
                                                    const float* __restrict__ B,
                                                    float* __restrict__ C,
                                                    const float* __restrict__ bias,
                                                    const float* __restrict__ residual) {
    __shared__ short As[64][40];
    __shared__ short Bs[64][40];
    int bm = blockIdx.y * 64, bn = blockIdx.x * 64;
    int tid = threadIdx.x;
    int wid = tid >> 6, lane = tid & 63;
    f32x4 acc[4] = {f32x4{0,0,0,0}, f32x4{0,0,0,0}, f32x4{0,0,0,0}, f32x4{0,0,0,0}};
    int ar = tid >> 2, akq = tid & 3;
    int bkk = tid >> 3, bng = tid & 7;
    for (int k0 = 0; k0 < DMODEL; k0 += 32) {
        {
            const short* src = A + (size_t)(bm + ar) * DMODEL + k0 + akq * 8;
            *(short8*)&As[ar][akq * 8] = *(const short8*)src;
        }
        {
            const float* src = B + (size_t)(k0 + bkk) * DMODEL + bn + bng * 8;
            f32x4 v0 = *(const f32x4*)src;
            f32x4 v1 = *(const f32x4*)(src + 4);
            for (int j = 0; j < 4; ++j) {
                Bs[bng * 8 + j][bkk] = f2bf(v0[j]);
                Bs[bng * 8 + 4 + j][bkk] = f2bf(v1[j]);
            }
        }
        __syncthreads();
        int row = wid * 16 + (lane & 15);
        int koff = (lane >> 4) * 8;
        short8 a = *(const short8*)&As[row][koff];
        for (int nf = 0; nf < 4; ++nf) {
            int col = nf * 16 + (lane & 15);
            short8 b = *(const short8*)&Bs[col][koff];
            acc[nf] = __builtin_amdgcn_mfma_f32_16x16x32_bf16(a, b, acc[nf], 0, 0, 0);
        }
        __syncthreads();
    }
    for (int nf = 0; nf < 4; ++nf) {
        int col = bn + nf * 16 + (lane & 15);
        for (int j = 0; j < 4; ++j) {
            int row = bm + wid * 16 + (lane >> 4) * 4 + j;
            C[(size_t)row * DMODEL + col] =
                acc[nf][j] + bias[col] + residual[(size_t)row * DMODEL + col];
        }
    }
}

extern "C" void kernel_launch(void* const* d_in, const int* in_sizes, int n_in,
                              void* d_out, int out_size, void* d_ws, size_t ws_size,
                              hipStream_t stream) {
    const float* q = (const float*)d_in[0];
    const float* k = (const float*)d_in[1];
    const float* v = (const float*)d_in[2];
    const float* Wq = (const float*)d_in[3];
    const float* Wk = (const float*)d_in[4];
    const float* Wv = (const float*)d_in[5];
    const float* Wfc = (const float*)d_in[6];
    const float* bfc = (const float*)d_in[7];
    const float* gamma = (const float*)d_in[8];
    const float* beta = (const float*)d_in[9];
    const float* rf = (const float*)d_in[10];
    float* out = (float*)d_out;

    float* ws = (float*)d_ws;
    short* attn = (short*)ws;                              // bf16 2048*512
    short* qh = attn + (size_t)NSEQ * DMODEL;              // bf16 2048*512
    short* kh = qh + (size_t)NSEQ * DMODEL;
    short* vhb = kh + (size_t)NSEQ * DMODEL;
    short* qp = vhb + (size_t)NSEQ * DMODEL;               // bf16 8*2048*288
    short* kp = qp + (size_t)NHEAD * NSEQ * MPAD;
    short* KVc = kp + (size_t)NHEAD * NSEQ * MPAD;         // bf16 8*32*64*288
    short* KVbT = KVc + (size_t)NHEAD * NT * DV * MPAD;
    float* Ks = (float*)(KVbT + (size_t)NHEAD * NT * DV * MPAD);   // fp32 8*32*288
    float* Ktot = Ks + (size_t)NHEAD * NT * MPAD;
    float* hk = Ktot + (size_t)NHEAD * MPAD;               // 8*2048
    float* partial = hk + (size_t)NHEAD * NSEQ;            // 256

    dim3 gq(DMODEL / 64, NSEQ / 64, 3);
    qkv_kernel<<<gq, 256, 0, stream>>>(q, k, v, Wq, Wk, Wv, gamma, beta,
                                       qh, kh, vhb, hk, partial);
    dim3 gf(NT, NHEAD, 2);
    feat_kernel<<<gf, 256, 0, stream>>>(qh, kh, rf, hk, partial, qp, kp);
    dim3 ga(NT, NHEAD);
    chunksum_kernel<<<ga, 256, 0, stream>>>(kp, vhb, KVc, Ks);
    int scan_threads = NHEAD * DV * MPAD + NHEAD * MPAD;
    scan_kernel<<<(scan_threads + 255) / 256, 256, 0, stream>>>(KVc, KVbT, Ks, Ktot);
    dim3 gc(NT, NHEAD);
    phasec_kernel<<<gc, 256, 0, stream>>>(qp, kp, vhb, KVbT, Ks, Ktot, attn);
    dim3 g(DMODEL / 64, NSEQ / 64);
    fgemm_kernel<<<g, 256, 0, stream>>>(attn, Wfc, out, bfc, q);
}

// Round 13
// 83.373 us; speedup vs baseline: 4.6342x; 1.0971x over previous
//
#include <hip/hip_runtime.h>
#include <math.h>

#define DMODEL 512
#define NSEQ 2048
#define NHEAD 8
#define DK 64
#define DV 64
#define MFEAT 266
#define MPAD 288        // padded feature dim for bf16 MFMA (zero tail), mult of 32
#define NT 32           // number of chunks (chunk = 64)
#define LN_EPS 1e-6f
#define KERNEL_EPS 1e-4f
#define NORM_STAB 1e-6f
#define SCALE 0.21022410381342863f  // 512^-0.25

typedef __attribute__((ext_vector_type(8))) short short8;
typedef __attribute__((ext_vector_type(4))) short sv4;
typedef __attribute__((ext_vector_type(4))) float f32x4;

__device__ inline short f2bf(float f) {
    unsigned u = __builtin_bit_cast(unsigned, f);
    unsigned r = (u + 0x7fff + ((u >> 16) & 1)) >> 16;
    return (short)r;
}
__device__ inline float bf2f(short s) {
    unsigned u = ((unsigned)(unsigned short)s) << 16;
    return __builtin_bit_cast(float, u);
}

// ============ fused QKV GEMM + random-feature map ============
// grid (8, 32, 3). z=0: LN(q)@Wq -> featQ -> qp. z=1: k@Wk -> h_k -> featK -> kp.
// z=2: v@Wv -> vh. k-stabilizer removed (cancels exactly up to O(KERNEL_EPS)):
// k_kernel = exp(h_k + proj_k); a uniform rescale of k' cancels between the
// numerator context and both denominators; only the additive eps breaks it (~1e-3).
__global__ __launch_bounds__(256) void qkvfeat_kernel(const float* __restrict__ qx,
                                                      const float* __restrict__ kx,
                                                      const float* __restrict__ vx,
                                                      const float* __restrict__ Wq,
                                                      const float* __restrict__ Wk,
                                                      const float* __restrict__ Wv,
                                                      const float* __restrict__ gamma,
                                                      const float* __restrict__ beta,
                                                      const float* __restrict__ rf,
                                                      short* __restrict__ vh,
                                                      short* __restrict__ qp,
                                                      short* __restrict__ kp) {
    __shared__ __align__(16) char smem[50944];
    auto As = (short(*)[40])smem;              // GEMM phase
    auto Bs = (short(*)[40])(smem + 5120);
    short* U = (short*)smem;                   // feat phase: rfb[288][72] then kp_lds[64][296]
    auto Xs = (short(*)[72])(smem + 41472);
    float* hks = (float*)(smem + 50688);       // 64 floats

    int z = blockIdx.z;
    const float* A = (z == 0) ? qx : (z == 1) ? kx : vx;
    const float* B = (z == 0) ? Wq : (z == 1) ? Wk : Wv;
    float scale = (z == 2) ? 1.f : SCALE;
    int bn = blockIdx.x * 64, bm = blockIdx.y * 64;
    int h = blockIdx.x, nt = blockIdx.y, n0 = nt * 64;
    int tid = threadIdx.x;
    int wid = tid >> 6, lane = tid & 63;
    f32x4 acc[4] = {f32x4{0,0,0,0}, f32x4{0,0,0,0}, f32x4{0,0,0,0}, f32x4{0,0,0,0}};
    int ar = tid >> 2, akq = tid & 3;
    int bkk = tid >> 3, bng = tid & 7;
    float lnm = 0.f, lnr = 0.f;
    if (z == 0) {
        // per-quad LN stats for row bm+ar (4 threads per row)
        const float* xr = qx + (size_t)(bm + ar) * DMODEL + akq * 128;
        float s = 0.f, ss = 0.f;
#pragma unroll 4
        for (int i = 0; i < 128; i += 4) {
            f32x4 vv = *(const f32x4*)(xr + i);
            s += vv[0] + vv[1] + vv[2] + vv[3];
            ss += vv[0]*vv[0] + vv[1]*vv[1] + vv[2]*vv[2] + vv[3]*vv[3];
        }
        s += __shfl_xor(s, 1); s += __shfl_xor(s, 2);
        ss += __shfl_xor(ss, 1); ss += __shfl_xor(ss, 2);
        float m = s / (float)DMODEL;
        float var = ss / (float)DMODEL - m * m;
        lnm = m;
        lnr = rsqrtf(var + LN_EPS);
    }
    for (int k0 = 0; k0 < DMODEL; k0 += 32) {
        {
            const float* src = A + (size_t)(bm + ar) * DMODEL + k0 + akq * 8;
            f32x4 v0 = *(const f32x4*)src;
            f32x4 v1 = *(const f32x4*)(src + 4);
            short8 sv;
            if (z == 0) {
                f32x4 g0 = *(const f32x4*)&gamma[k0 + akq * 8];
                f32x4 g1 = *(const f32x4*)&gamma[k0 + akq * 8 + 4];
                f32x4 bb0 = *(const f32x4*)&beta[k0 + akq * 8];
                f32x4 bb1 = *(const f32x4*)&beta[k0 + akq * 8 + 4];
                for (int j = 0; j < 4; ++j) {
                    sv[j] = f2bf((v0[j] - lnm) * lnr * g0[j] + bb0[j]);
                    sv[4 + j] = f2bf((v1[j] - lnm) * lnr * g1[j] + bb1[j]);
                }
            } else {
                for (int j = 0; j < 4; ++j) { sv[j] = f2bf(v0[j]); sv[4 + j] = f2bf(v1[j]); }
            }
            *(short8*)&As[ar][akq * 8] = sv;
        }
        {
            const float* src = B + (size_t)(k0 + bkk) * DMODEL + bn + bng * 8;
            f32x4 v0 = *(const f32x4*)src;
            f32x4 v1 = *(const f32x4*)(src + 4);
            for (int j = 0; j < 4; ++j) {
                Bs[bng * 8 + j][bkk] = f2bf(v0[j] * scale);
                Bs[bng * 8 + 4 + j][bkk] = f2bf(v1[j] * scale);
            }
        }
        __syncthreads();
        int row = wid * 16 + (lane & 15);
        int koff = (lane >> 4) * 8;
        short8 a = *(const short8*)&As[row][koff];
        for (int nf = 0; nf < 4; ++nf) {
            int col = nf * 16 + (lane & 15);
            short8 b = *(const short8*)&Bs[col][koff];
            acc[nf] = __builtin_amdgcn_mfma_f32_16x16x32_bf16(a, b, acc[nf], 0, 0, 0);
        }
        __syncthreads();
    }
    if (z == 2) {
        // V path: write vh and exit
        for (int nf = 0; nf < 4; ++nf) {
            int col = bn + nf * 16 + (lane & 15);
            for (int j = 0; j < 4; ++j) {
                int row = bm + wid * 16 + (lane >> 4) * 4 + j;
                vh[(size_t)row * DMODEL + col] = f2bf(acc[nf][j]);
            }
        }
        return;
    }
    // ---- feat phase: C tile -> Xs (bf16, same rounding as old HBM handoff) ----
    for (int nf = 0; nf < 4; ++nf) {
        int col = nf * 16 + (lane & 15);
        for (int j = 0; j < 4; ++j) {
            int row = wid * 16 + (lane >> 4) * 4 + j;
            Xs[row][col] = f2bf(acc[nf][j]);
        }
    }
    if (z == 1) {
        // local h_k per row from fp32 accumulators
        for (int j = 0; j < 4; ++j) {
            float ss = 0.f;
            for (int nf = 0; nf < 4; ++nf) ss += acc[nf][j] * acc[nf][j];
            for (int o = 1; o < 16; o <<= 1) ss += __shfl_xor(ss, o);
            if ((lane & 15) == 0) hks[wid * 16 + (lane >> 4) * 4 + j] = -0.5f * ss;
        }
    }
    // stage rf -> bf16 rfb[m][d] (zero for m>=MFEAT); overlaps dead As/Bs
    short (*rfb)[72] = (short(*)[72])U;
    for (int lp = 0; lp < 5; ++lp) {
        int c = tid + lp * 256;
        if (c < 288 * 4) {
            int m = c >> 2, dq = (c & 3) * 16;
            short8 s0, s1;
            if (m < MFEAT) {
                f32x4 v0 = *(const f32x4*)&rf[(size_t)m * DK + dq];
                f32x4 v1 = *(const f32x4*)&rf[(size_t)m * DK + dq + 4];
                f32x4 v2 = *(const f32x4*)&rf[(size_t)m * DK + dq + 8];
                f32x4 v3 = *(const f32x4*)&rf[(size_t)m * DK + dq + 12];
                for (int j = 0; j < 4; ++j) {
                    s0[j] = f2bf(v0[j]); s0[4 + j] = f2bf(v1[j]);
                    s1[j] = f2bf(v2[j]); s1[4 + j] = f2bf(v3[j]);
                }
            } else {
                for (int j = 0; j < 8; ++j) { s0[j] = 0; s1[j] = 0; }
            }
            *(short8*)&rfb[m][dq] = s0;
            *(short8*)&rfb[m][dq + 8] = s1;
        }
    }
    __syncthreads();

    // proj MFMA: C[m][n] = sum_d rfb[m][d] * Xs[n][d]; wave w owns n-tile w
    int w = wid, l = lane;
    int fr = l & 15, fq = (l >> 4) * 8;
    short8 xb0 = *(const short8*)&Xs[w * 16 + fr][fq];
    short8 xb1 = *(const short8*)&Xs[w * 16 + fr][32 + fq];
    f32x4 facc[18];
#pragma unroll
    for (int tr = 0; tr < 18; ++tr) facc[tr] = f32x4{0, 0, 0, 0};
#pragma unroll
    for (int tr = 0; tr < 18; ++tr) {
        short8 a0 = *(const short8*)&rfb[tr * 16 + fr][fq];
        short8 a1 = *(const short8*)&rfb[tr * 16 + fr][32 + fq];
        facc[tr] = __builtin_amdgcn_mfma_f32_16x16x32_bf16(a0, xb0, facc[tr], 0, 0, 0);
        facc[tr] = __builtin_amdgcn_mfma_f32_16x16x32_bf16(a1, xb1, facc[tr], 0, 0, 0);
    }
    int n_loc = w * 16 + fr;
    float hval = (z == 1) ? hks[n_loc] : 0.f;
    __syncthreads();  // rfb reads done; U becomes kp_lds

    short (*kpl)[296] = (short(*)[296])U;
    const float cnorm = 0.06131393394849658f;  // 266^-0.5
#pragma unroll
    for (int tr = 0; tr < 18; ++tr) {
        sv4 o;
        for (int j = 0; j < 4; ++j) {
            int m = tr * 16 + (l >> 4) * 4 + j;
            float val = (m < MFEAT) ? cnorm * (expf(facc[tr][j] + hval) + KERNEL_EPS) : 0.f;
            o[j] = f2bf(val);
        }
        *(sv4*)&kpl[n_loc][tr * 16 + (l >> 4) * 4] = o;
    }
    __syncthreads();
    // coalesced copy kp_lds rows -> HBM
    short* outp = (z == 0) ? qp : kp;
    for (int lp = 0; lp < 9; ++lp) {
        int c = tid + lp * 256;      // 64 rows * 36 chunks
        int nn = c / 36, c8 = c % 36;
        short8 v = *(const short8*)&kpl[nn][c8 * 8];
        *(short8*)&outp[((size_t)h * NSEQ + n0 + nn) * MPAD + c8 * 8] = v;
    }
}

// ---------------- phase A (MFMA): per-chunk sums -> bf16 KVc[(h,t,dv)][m], fp32 Ks[(h,t)][m] ----------------
__global__ __launch_bounds__(256) void chunksum_kernel(const short* __restrict__ kp,
                                                       const short* __restrict__ vh,
                                                       short* __restrict__ KVc,
                                                       float* __restrict__ Ks) {
    int t = blockIdx.x, h = blockIdx.y;
    __shared__ short kpT[288 * 72];   // [m][i-swizzled], stride 72 shorts (144B); 41.5KB
    __shared__ short Vt[64][72];      // [dv][i]
    int tid = threadIdx.x;
    int w = tid >> 6, l = tid & 63;
    int fr = l & 15, fq8 = (l >> 4) * 8;
    const short* kpb = kp + ((size_t)h * NSEQ + (size_t)t * 64) * MPAD;

    // stage kp^T: read rows coalesced, scatter to swizzled columns
    for (int lp = 0; lp < 9; ++lp) {
        int c = tid + lp * 256;       // 2304 = 64 i * 36 m-chunks
        int i = c / 36, c8 = c % 36;
        short8 v = *(const short8*)&kpb[(size_t)i * MPAD + c8 * 8];
        int i8 = i >> 3, i7 = i & 7;
        for (int jj = 0; jj < 8; ++jj) {
            int m = c8 * 8 + jj;
            int ig = i8 ^ ((m >> 3) & 7);
            kpT[m * 72 + ig * 8 + i7] = v[jj];
        }
    }
    // stage V^T
    for (int lp = 0; lp < 2; ++lp) {
        int c = tid + lp * 256;       // 512 = 64 i * 8 d-chunks
        int i = c & 63, d8 = (c >> 6) * 8;
        short8 v = *(const short8*)&vh[(size_t)(t * 64 + i) * DMODEL + h * DV + d8];
        for (int jj = 0; jj < 8; ++jj) Vt[d8 + jj][i] = v[jj];
    }
    __syncthreads();

    // D[m][dv] = sum_i kp^T[m][i] * V[i][dv]; wave w owns m-tiles {w, w+4, ...}
    f32x4 acc[5][4];
#pragma unroll
    for (int tt = 0; tt < 5; ++tt)
        for (int nf = 0; nf < 4; ++nf) acc[tt][nf] = f32x4{0, 0, 0, 0};
#pragma unroll
    for (int tt = 0; tt < 5; ++tt) {
        int tr = w + tt * 4;
        if (tr < 18) {
            int row = tr * 16 + fr;
            int swz = (row >> 3) & 7;
            short8 a0 = *(const short8*)&kpT[row * 72 + (((fq8 >> 3)) ^ swz) * 8];
            short8 a1 = *(const short8*)&kpT[row * 72 + ((4 + (fq8 >> 3)) ^ swz) * 8];
            for (int nf = 0; nf < 4; ++nf) {
                short8 b0 = *(const short8*)&Vt[nf * 16 + fr][fq8];
                short8 b1 = *(const short8*)&Vt[nf * 16 + fr][32 + fq8];
                acc[tt][nf] = __builtin_amdgcn_mfma_f32_16x16x32_bf16(a0, b0, acc[tt][nf], 0, 0, 0);
                acc[tt][nf] = __builtin_amdgcn_mfma_f32_16x16x32_bf16(a1, b1, acc[tt][nf], 0, 0, 0);
            }
        }
    }
    // Ks[m] = sum_i kp^T[m][i]
    for (int m = tid; m < MPAD; m += 256) {
        int swz = (m >> 3) & 7;
        float s = 0.f;
        for (int i8 = 0; i8 < 8; ++i8) {
            int ig = i8 ^ swz;
            for (int j = 0; j < 8; ++j) s += bf2f(kpT[m * 72 + ig * 8 + j]);
        }
        Ks[((size_t)h * NT + t) * MPAD + m] = s;
    }
    __syncthreads();  // kpT reads done; overlay kvT
    short* kvT = kpT; // [64 dv][296 m]
#pragma unroll
    for (int tt = 0; tt < 5; ++tt) {
        int tr = w + tt * 4;
        if (tr < 18) {
            for (int nf = 0; nf < 4; ++nf) {
                int dv = nf * 16 + fr;
                for (int j = 0; j < 4; ++j) {
                    int m = tr * 16 + (l >> 4) * 4 + j;
                    kvT[dv * 296 + m] = f2bf(acc[tt][nf][j]);
                }
            }
        }
    }
    __syncthreads();
    // coalesced KVc store
    for (int lp = 0; lp < 9; ++lp) {
        int c = tid + lp * 256;       // 2304 = 64 dv * 36
        int dv = c / 36, c8 = c % 36;
        short8 v = *(const short8*)&kvT[dv * 296 + c8 * 8];
        *(short8*)&KVc[(((size_t)h * NT + t) * DV + dv) * MPAD + c8 * 8] = v;
    }
}

// ---------------- fused exclusive chunk-scans, batched loads ----------------
__global__ __launch_bounds__(256) void scan_kernel(const short* __restrict__ KVc,
                                                   short* __restrict__ KVbT,
                                                   float* __restrict__ Ks,
                                                   float* __restrict__ Ktot) {
    int idx = blockIdx.x * 256 + threadIdx.x;
    const int NKV = NHEAD * DV * MPAD;       // 147456
    if (idx < NKV) {
        int h = idx / (DV * MPAD);
        int rem = idx % (DV * MPAD);
        size_t base = (size_t)h * NT * DV * MPAD + rem;
        short vals[NT];
#pragma unroll
        for (int t = 0; t < NT; ++t) vals[t] = KVc[base + (size_t)t * DV * MPAD];
        float run = 0.f;
#pragma unroll
        for (int t = 0; t < NT; ++t) {
            KVbT[base + (size_t)t * DV * MPAD] = f2bf(run);
            run += bf2f(vals[t]);
        }
    } else {
        int j = idx - NKV;
        if (j < NHEAD * MPAD) {
            int h = j / MPAD, m = j % MPAD;
            size_t base = (size_t)h * NT * MPAD + m;
            float vals[NT];
#pragma unroll
            for (int t = 0; t < NT; ++t) vals[t] = Ks[base + (size_t)t * MPAD];
            float run = 0.f;
#pragma unroll
            for (int t = 0; t < NT; ++t) {
                Ks[base + (size_t)t * MPAD] = run;
                run += vals[t];
            }
            Ktot[(size_t)h * MPAD + m] = run;
        }
    }
}

// ---------------- phase C: MFMA intra+inter+denominators; bf16 out ----------------
__global__ __launch_bounds__(256) void phasec_kernel(const short* __restrict__ qp,
                                                     const short* __restrict__ kp,
                                                     const short* __restrict__ vh,
                                                     const short* __restrict__ KVbT,
                                                     const float* __restrict__ Ks,
                                                     const float* __restrict__ Ktot,
                                                     short* __restrict__ attn) {
    int t = blockIdx.x, h = blockIdx.y;
    __shared__ short Buf[64][296];   // Kp (QK^T phase) then St (inter phase)
    __shared__ short Vt[64][72];     // [dv][i]
    __shared__ short Am[64][72];     // masked A, bf16
    __shared__ float Ksp[MPAD], Ktp[MPAD];
    __shared__ float fscale_s[64];
    int tid = threadIdx.x;
    int w = tid >> 6, l = tid & 63;
    int fr = l & 15, fq = (l >> 4) * 8;
    const short* qpb = qp + ((size_t)h * NSEQ + (size_t)t * 64) * MPAD;
    const short* kpb = kp + ((size_t)h * NSEQ + (size_t)t * 64) * MPAD;
    const short* stb = KVbT + ((size_t)h * NT + t) * DV * MPAD;

    short8 qf[9];
#pragma unroll
    for (int ks = 0; ks < 9; ++ks)
        qf[ks] = *(const short8*)&qpb[(size_t)(w * 16 + fr) * MPAD + ks * 32 + fq];

    int srow = tid >> 2, sc4 = tid & 3;
#pragma unroll
    for (int lp = 0; lp < 9; ++lp) {
        int c = sc4 + lp * 4;
        *(short8*)&Buf[srow][c * 8] = *(const short8*)&kpb[(size_t)srow * MPAD + c * 8];
    }
    // stage Vt via row reads + LDS transpose
    for (int lp = 0; lp < 2; ++lp) {
        int c = tid + lp * 256;
        int i = c & 63, d8 = (c >> 6) * 8;
        short8 v = *(const short8*)&vh[(size_t)(t * 64 + i) * DMODEL + h * DV + d8];
        for (int jj = 0; jj < 8; ++jj) Vt[d8 + jj][i] = v[jj];
    }
    for (int idx = tid; idx < MPAD; idx += 256) {
        Ksp[idx] = Ks[((size_t)h * NT + t) * MPAD + idx];
        Ktp[idx] = Ktot[(size_t)h * MPAD + idx];
    }
    // async-issue S^T loads; latency hides under QK^T MFMAs
    short8 stg[9];
#pragma unroll
    for (int lp = 0; lp < 9; ++lp) {
        int c = sc4 + lp * 4;
        stg[lp] = *(const short8*)&stb[(size_t)srow * MPAD + c * 8];
    }
    __syncthreads();

    f32x4 accA[4] = {f32x4{0,0,0,0}, f32x4{0,0,0,0}, f32x4{0,0,0,0}, f32x4{0,0,0,0}};
    f32x4 accO[4] = {f32x4{0,0,0,0}, f32x4{0,0,0,0}, f32x4{0,0,0,0}, f32x4{0,0,0,0}};
#pragma unroll 3
    for (int ks = 0; ks < 9; ++ks) {
        int ko = ks * 32 + fq;
        for (int nf = 0; nf < 4; ++nf) {
            short8 bk = *(const short8*)&Buf[nf * 16 + fr][ko];
            accA[nf] = __builtin_amdgcn_mfma_f32_16x16x32_bf16(qf[ks], bk, accA[nf], 0, 0, 0);
        }
    }
    __syncthreads();
#pragma unroll
    for (int lp = 0; lp < 9; ++lp) {
        int c = sc4 + lp * 4;
        *(short8*)&Buf[srow][c * 8] = stg[lp];
    }
    for (int nf = 0; nf < 4; ++nf) {
        int col = nf * 16 + fr;
        for (int j = 0; j < 4; ++j) {
            int row = w * 16 + (l >> 4) * 4 + j;
            Am[row][col] = (col <= row) ? f2bf(accA[nf][j]) : (short)0;
        }
    }
    __syncthreads();
#pragma unroll 3
    for (int ks = 0; ks < 9; ++ks) {
        int ko = ks * 32 + fq;
        for (int nf = 0; nf < 4; ++nf) {
            short8 bs = *(const short8*)&Buf[nf * 16 + fr][ko];
            accO[nf] = __builtin_amdgcn_mfma_f32_16x16x32_bf16(qf[ks], bs, accO[nf], 0, 0, 0);
        }
    }
#pragma unroll
    for (int ks = 0; ks < 2; ++ks) {
        int ko = ks * 32 + fq;
        short8 a = *(const short8*)&Am[w * 16 + fr][ko];
        for (int nf = 0; nf < 4; ++nf) {
            short8 b = *(const short8*)&Vt[nf * 16 + fr][ko];
            accO[nf] = __builtin_amdgcn_mfma_f32_16x16x32_bf16(a, b, accO[nf], 0, 0, 0);
        }
    }
    int di = tid >> 2, dp = tid & 3;
    float dc = 0.f, df = 0.f;
    {
        const short* amrow = &Am[di][dp * 16];
        short8 s0 = *(const short8*)amrow;
        short8 s1 = *(const short8*)(amrow + 8);
        for (int j2 = 0; j2 < 8; ++j2) dc += bf2f(s0[j2]) + bf2f(s1[j2]);
    }
#pragma unroll
    for (int c8 = 0; c8 < 9; ++c8) {
        int m = dp * 72 + c8 * 8;
        short8 qv = *(const short8*)&qpb[(size_t)di * MPAD + m];
        for (int j2 = 0; j2 < 8; ++j2) {
            float qq = bf2f(qv[j2]);
            dc += qq * Ksp[m + j2];
            df += qq * Ktp[m + j2];
        }
    }
    dc += __shfl_xor(dc, 1); dc += __shfl_xor(dc, 2);
    df += __shfl_xor(df, 1); df += __shfl_xor(df, 2);
    if (dp == 0) {
        float dst = df;
        if (fabsf(dst) <= NORM_STAB) dst += 2.f * NORM_STAB;
        fscale_s[di] = (1.f / dc) / dst;
    }
    __syncthreads();
    for (int nf = 0; nf < 4; ++nf) {
        int col = nf * 16 + fr;
        for (int j = 0; j < 4; ++j) {
            int row = w * 16 + (l >> 4) * 4 + j;
            attn[((size_t)t * 64 + row) * DMODEL + h * DV + col] =
                f2bf(accO[nf][j] * fscale_s[row]);
        }
    }
}

// ---------------- final GEMM with bias + residual (A is bf16) ----------------
__global__ __launch_bounds__(256) void fgemm_kernel(const short* __restrict__ A,
                                                    const float* __restrict__ B,
                                                    float* __restrict__ C,
                                                    const float* __restrict__ bias,
                                                    const float* __restrict__ residual) {
    __shared__ short As[64][40];
    __shared__ short Bs[64][40];
    int bm = blockIdx.y * 64, bn = blockIdx.x * 64;
    int tid = threadIdx.x;
    int wid = tid >> 6, lane = tid & 63;
    f32x4 acc[4] = {f32x4{0,0,0,0}, f32x4{0,0,0,0}, f32x4{0,0,0,0}, f32x4{0,0,0,0}};
    int ar = tid >> 2, akq = tid & 3;
    int bkk = tid >> 3, bng = tid & 7;
    for (int k0 = 0; k0 < DMODEL; k0 += 32) {
        {
            const short* src = A + (size_t)(bm + ar) * DMODEL + k0 + akq * 8;
            *(short8*)&As[ar][akq * 8] = *(const short8*)src;
        }
        {
            const float* src = B + (size_t)(k0 + bkk) * DMODEL + bn + bng * 8;
            f32x4 v0 = *(const f32x4*)src;
            f32x4 v1 = *(const f32x4*)(src + 4);
            for (int j = 0; j < 4; ++j) {
                Bs[bng * 8 + j][bkk] = f2bf(v0[j]);
                Bs[bng * 8 + 4 + j][bkk] = f2bf(v1[j]);
            }
        }
        __syncthreads();
        int row = wid * 16 + (lane & 15);
        int koff = (lane >> 4) * 8;
        short8 a = *(const short8*)&As[row][koff];
        for (int nf = 0; nf < 4; ++nf) {
            int col = nf * 16 + (lane & 15);
            short8 b = *(const short8*)&Bs[col][koff];
            acc[nf] = __builtin_amdgcn_mfma_f32_16x16x32_bf16(a, b, acc[nf], 0, 0, 0);
        }
        __syncthreads();
    }
    for (int nf = 0; nf < 4; ++nf) {
        int col = bn + nf * 16 + (lane & 15);
        for (int j = 0; j < 4; ++j) {
            int row = bm + wid * 16 + (lane >> 4) * 4 + j;
            C[(size_t)row * DMODEL + col] =
                acc[nf][j] + bias[col] + residual[(size_t)row * DMODEL + col];
        }
    }
}

extern "C" void kernel_launch(void* const* d_in, const int* in_sizes, int n_in,
                              void* d_out, int out_size, void* d_ws, size_t ws_size,
                              hipStream_t stream) {
    const float* q = (const float*)d_in[0];
    const float* k = (const float*)d_in[1];
    const float* v = (const float*)d_in[2];
    const float* Wq = (const float*)d_in[3];
    const float* Wk = (const float*)d_in[4];
    const float* Wv = (const float*)d_in[5];
    const float* Wfc = (const float*)d_in[6];
    const float* bfc = (const float*)d_in[7];
    const float* gamma = (const float*)d_in[8];
    const float* beta = (const float*)d_in[9];
    const float* rf = (const float*)d_in[10];
    float* out = (float*)d_out;

    float* ws = (float*)d_ws;
    short* attn = (short*)ws;                              // bf16 2048*512
    short* vhb = attn + (size_t)NSEQ * DMODEL;             // bf16 2048*512
    short* qp = vhb + (size_t)NSEQ * DMODEL;               // bf16 8*2048*288
    short* kp = qp + (size_t)NHEAD * NSEQ * MPAD;
    short* KVc = kp + (size_t)NHEAD * NSEQ * MPAD;         // bf16 8*32*64*288
    short* KVbT = KVc + (size_t)NHEAD * NT * DV * MPAD;
    float* Ks = (float*)(KVbT + (size_t)NHEAD * NT * DV * MPAD);   // fp32 8*32*288
    float* Ktot = Ks + (size_t)NHEAD * NT * MPAD;          // 8*288

    dim3 gq(NHEAD, NSEQ / 64, 3);
    qkvfeat_kernel<<<gq, 256, 0, stream>>>(q, k, v, Wq, Wk, Wv, gamma, beta, rf,
                                           vhb, qp, kp);
    dim3 ga(NT, NHEAD);
    chunksum_kernel<<<ga, 256, 0, stream>>>(kp, vhb, KVc, Ks);
    int scan_threads = NHEAD * DV * MPAD + NHEAD * MPAD;
    scan_kernel<<<(scan_threads + 255) / 256, 256, 0, stream>>>(KVc, KVbT, Ks, Ktot);
    dim3 gc(NT, NHEAD);
    phasec_kernel<<<gc, 256, 0, stream>>>(qp, kp, vhb, KVbT, Ks, Ktot, attn);
    dim3 g(DMODEL / 64, NSEQ / 64);
    fgemm_kernel<<<g, 256, 0, stream>>>(attn, Wfc, out, bfc, q);
}